// Round 1
// baseline (156.915 us; speedup 1.0000x reference)
//
#include <hip/hip_runtime.h>
#include <stdint.h>

#define MARGIN 0.3f

typedef __bf16 bf16x8_t __attribute__((ext_vector_type(8)));
typedef float f32x4_t __attribute__((ext_vector_type(4)));

static constexpr int NB = 4096;   // batch
static constexpr int ND = 1024;   // feature dim
static constexpr int BM = 128;
static constexpr int BN = 128;
static constexpr int BK = 64;

// RNE float->bf16 (no NaN path needed for this data)
__device__ __forceinline__ unsigned short f2bf(float x) {
  union { float f; unsigned u; } v; v.f = x;
  unsigned r = v.u + 0x7FFFu + ((v.u >> 16) & 1u);
  return (unsigned short)(r >> 16);
}

__device__ __forceinline__ void gload_lds16(const void* g, void* l) {
  __builtin_amdgcn_global_load_lds(
      reinterpret_cast<const __attribute__((address_space(1))) uint32_t*>(
          reinterpret_cast<uintptr_t>(g)),
      reinterpret_cast<__attribute__((address_space(3))) uint32_t*>(
          reinterpret_cast<uintptr_t>(l)),
      16, 0, 0);
}

// ---- Kernel 1: fused row-normalize (fp32 stats, bf16 out) + stat init ----
__global__ __launch_bounds__(256) void norm_kernel(
    const float* __restrict__ za, const float* __restrict__ zp,
    __bf16* __restrict__ Ah, __bf16* __restrict__ Ph,
    float* __restrict__ pos, float* __restrict__ ssum,
    int* __restrict__ scnt, unsigned* __restrict__ smin) {
  const int b = blockIdx.x;
  const int t = threadIdx.x;
  const float4 av = reinterpret_cast<const float4*>(za + (size_t)b * ND)[t];
  const float4 pv = reinterpret_cast<const float4*>(zp + (size_t)b * ND)[t];
  float sa = av.x * av.x + av.y * av.y + av.z * av.z + av.w * av.w;
  float sp = pv.x * pv.x + pv.y * pv.y + pv.z * pv.z + pv.w * pv.w;
  float dp = av.x * pv.x + av.y * pv.y + av.z * pv.z + av.w * pv.w;
#pragma unroll
  for (int off = 1; off < 64; off <<= 1) {
    sa += __shfl_xor(sa, off);
    sp += __shfl_xor(sp, off);
    dp += __shfl_xor(dp, off);
  }
  __shared__ float red[3][4];
  const int wid = t >> 6, lane = t & 63;
  if (lane == 0) { red[0][wid] = sa; red[1][wid] = sp; red[2][wid] = dp; }
  __syncthreads();
  sa = red[0][0] + red[0][1] + red[0][2] + red[0][3];
  sp = red[1][0] + red[1][1] + red[1][2] + red[1][3];
  dp = red[2][0] + red[2][1] + red[2][2] + red[2][3];
  const float rsa = rsqrtf(sa), rsp = rsqrtf(sp);
  if (t == 0) {
    pos[b] = 1.0f - dp * rsa * rsp;
    ssum[b] = 0.0f;
    scnt[b] = 0;
    smin[b] = 0x7F800000u;  // +inf bits; all offdiag (1-dot) values are > 0
  }
  ushort4 oa, op;
  oa.x = f2bf(av.x * rsa); oa.y = f2bf(av.y * rsa);
  oa.z = f2bf(av.z * rsa); oa.w = f2bf(av.w * rsa);
  op.x = f2bf(pv.x * rsp); op.y = f2bf(pv.y * rsp);
  op.z = f2bf(pv.z * rsp); op.w = f2bf(pv.w * rsp);
  reinterpret_cast<ushort4*>(reinterpret_cast<unsigned short*>(Ah) + (size_t)b * ND)[t] = oa;
  reinterpret_cast<ushort4*>(reinterpret_cast<unsigned short*>(Ph) + (size_t)b * ND)[t] = op;
}

// ---- Kernel 2: S = Ah . Ph^T fused with per-row semi-hard stats ----------
// m97-style: 128x128 tile, BK=64, 4 waves (2x2), global_load_lds width-16,
// 16x16x32 bf16 MFMA, 2 barriers per K-step, epilogue shuffle-reduce + atomics.
__global__ __launch_bounds__(256) void gemm_stats_kernel(
    const __bf16* __restrict__ Ah, const __bf16* __restrict__ Ph,
    const float* __restrict__ pos, float* __restrict__ ssum,
    int* __restrict__ scnt, unsigned* __restrict__ smin) {
  __shared__ __align__(16) __bf16 As[BM * BK];
  __shared__ __align__(16) __bf16 Bs[BN * BK];
  const int t = threadIdx.x;
  const int lane = t & 63;
  const int wid = t >> 6;
  const int wr = wid >> 1, wc = wid & 1;
  const int g = lane >> 4, c = lane & 15;
  const int row0 = blockIdx.y * BM;
  const int col0 = blockIdx.x * BN;

  f32x4_t acc[4][4] = {};

  // staging map: call i, thread t -> LDS elem i*2048 + t*8 = row (i*32+t/8), k (t%8)*8
  const int sr = t >> 3;
  const int sk = (t & 7) * 8;
  const __bf16* Ag = Ah + (size_t)(row0 + sr) * ND + sk;
  const __bf16* Bg = Ph + (size_t)(col0 + sr) * ND + sk;

  for (int kt = 0; kt < ND / BK; ++kt) {
    __syncthreads();
    const __bf16* Agk = Ag + kt * BK;
    const __bf16* Bgk = Bg + kt * BK;
#pragma unroll
    for (int i = 0; i < 4; ++i) {
      gload_lds16(Agk + (size_t)i * 32 * ND, As + i * 2048 + wid * 512);
      gload_lds16(Bgk + (size_t)i * 32 * ND, Bs + i * 2048 + wid * 512);
    }
    __syncthreads();  // compiler drains vmcnt(0) here -> LDS valid
#pragma unroll
    for (int kk = 0; kk < 2; ++kk) {
      bf16x8_t af[4], bfv[4];
#pragma unroll
      for (int m = 0; m < 4; ++m)
        af[m] = *reinterpret_cast<const bf16x8_t*>(
            As + (wr * 64 + m * 16 + c) * BK + kk * 32 + g * 8);
#pragma unroll
      for (int n = 0; n < 4; ++n)
        bfv[n] = *reinterpret_cast<const bf16x8_t*>(
            Bs + (wc * 64 + n * 16 + c) * BK + kk * 32 + g * 8);
#pragma unroll
      for (int m = 0; m < 4; ++m)
#pragma unroll
        for (int n = 0; n < 4; ++n)
          acc[m][n] = __builtin_amdgcn_mfma_f32_16x16x32_bf16(
              af[m], bfv[n], acc[m][n], 0, 0, 0);
    }
  }

  // epilogue: per-row {sum,cnt,min} over this block's 128-col slice
  // D layout: col = lane&15 (c), row = (lane>>4)*4 + reg (g*4+r)
#pragma unroll
  for (int m = 0; m < 4; ++m) {
#pragma unroll
    for (int r = 0; r < 4; ++r) {
      const int grow = row0 + wr * 64 + m * 16 + g * 4 + r;
      const float pd = pos[grow];
      float s = 0.0f;
      int ct = 0;
      float mn = 3.0e38f;
#pragma unroll
      for (int n = 0; n < 4; ++n) {
        const int gcol = col0 + wc * 64 + n * 16 + c;
        const float v = 1.0f - acc[m][n][r];
        if (gcol != grow) {
          mn = fminf(mn, v);
          if (v > pd && v < pd + MARGIN) { s += v; ct += 1; }
        }
      }
      // reduce across the 16 cols held by lanes sharing g (xor keeps g fixed)
#pragma unroll
      for (int off = 1; off < 16; off <<= 1) {
        s += __shfl_xor(s, off);
        ct += __shfl_xor(ct, off);
        mn = fminf(mn, __shfl_xor(mn, off));
      }
      if (c == 0) {
        atomicAdd(&ssum[grow], s);
        atomicAdd(&scnt[grow], ct);
        atomicMin(&smin[grow], __float_as_uint(mn));  // positive floats: uint order == float order
      }
    }
  }
}

// ---- Kernel 3: combine per-row stats -> loss -----------------------------
__global__ __launch_bounds__(256) void finalize_kernel(
    const float* __restrict__ pos, const float* __restrict__ ssum,
    const int* __restrict__ scnt, const unsigned* __restrict__ smin,
    float* __restrict__ out) {
  const int t = threadIdx.x;
  float acc = 0.0f;
  for (int rr = t; rr < NB; rr += 256) {
    const float pd = pos[rr];
    const int ct = scnt[rr];
    const float neg = ct > 0 ? ssum[rr] / (float)ct : __uint_as_float(smin[rr]);
    acc += fmaxf(pd - neg + MARGIN, 0.0f);
  }
#pragma unroll
  for (int off = 1; off < 64; off <<= 1) acc += __shfl_xor(acc, off);
  __shared__ float red[4];
  if ((t & 63) == 0) red[t >> 6] = acc;
  __syncthreads();
  if (t == 0) out[0] = (red[0] + red[1] + red[2] + red[3]) * (1.0f / NB);
}

extern "C" void kernel_launch(void* const* d_in, const int* in_sizes, int n_in,
                              void* d_out, int out_size, void* d_ws, size_t ws_size,
                              hipStream_t stream) {
  const float* za = (const float*)d_in[0];
  const float* zp = (const float*)d_in[1];
  float* out = (float*)d_out;
  char* ws = (char*)d_ws;
  __bf16* Ah = (__bf16*)(ws);                                   // 8 MB
  __bf16* Ph = (__bf16*)(ws + (size_t)NB * ND * 2);             // 8 MB
  float* pos = (float*)(ws + (size_t)NB * ND * 4);              // 16 KB
  float* ssum = pos + NB;                                       // 16 KB
  int* scnt = (int*)(ssum + NB);                                // 16 KB
  unsigned* smin = (unsigned*)(scnt + NB);                      // 16 KB

  norm_kernel<<<NB, 256, 0, stream>>>(za, zp, Ah, Ph, pos, ssum, scnt, smin);
  gemm_stats_kernel<<<dim3(NB / BN, NB / BM), 256, 0, stream>>>(
      Ah, Ph, pos, ssum, scnt, smin);
  finalize_kernel<<<1, 256, 0, stream>>>(pos, ssum, scnt, smin, out);
}

// Round 2
// 133.800 us; speedup vs baseline: 1.1728x; 1.1728x over previous
//
#include <hip/hip_runtime.h>
#include <stdint.h>

#define MARGIN 0.3f

typedef __bf16 bf16x8_t __attribute__((ext_vector_type(8)));
typedef float f32x4_t __attribute__((ext_vector_type(4)));

static constexpr int NB = 4096;   // batch
static constexpr int ND = 1024;   // feature dim
static constexpr int NKT = ND / 64;  // 16 K-tiles of BK=64
static constexpr int NIT = NKT / 2;  // 8 main-loop iterations

// RNE float->bf16
__device__ __forceinline__ unsigned short f2bf(float x) {
  union { float f; unsigned u; } v; v.f = x;
  unsigned r = v.u + 0x7FFFu + ((v.u >> 16) & 1u);
  return (unsigned short)(r >> 16);
}

__device__ __forceinline__ void gload_lds16(const void* g, void* l) {
  __builtin_amdgcn_global_load_lds(
      reinterpret_cast<const __attribute__((address_space(1))) uint32_t*>(
          reinterpret_cast<uintptr_t>(g)),
      reinterpret_cast<__attribute__((address_space(3))) uint32_t*>(
          reinterpret_cast<uintptr_t>(l)),
      16, 0, 0);
}

// ---- Kernel 1: fused row-normalize (fp32 stats, bf16 out) + stat init ----
__global__ __launch_bounds__(256) void norm_kernel(
    const float* __restrict__ za, const float* __restrict__ zp,
    __bf16* __restrict__ Ah, __bf16* __restrict__ Ph,
    float* __restrict__ pos, float* __restrict__ ssum,
    int* __restrict__ scnt, unsigned* __restrict__ smin) {
  const int b = blockIdx.x;
  const int t = threadIdx.x;
  const float4 av = reinterpret_cast<const float4*>(za + (size_t)b * ND)[t];
  const float4 pv = reinterpret_cast<const float4*>(zp + (size_t)b * ND)[t];
  float sa = av.x * av.x + av.y * av.y + av.z * av.z + av.w * av.w;
  float sp = pv.x * pv.x + pv.y * pv.y + pv.z * pv.z + pv.w * pv.w;
  float dp = av.x * pv.x + av.y * pv.y + av.z * pv.z + av.w * pv.w;
#pragma unroll
  for (int off = 1; off < 64; off <<= 1) {
    sa += __shfl_xor(sa, off);
    sp += __shfl_xor(sp, off);
    dp += __shfl_xor(dp, off);
  }
  __shared__ float red[3][4];
  const int wid = t >> 6, lane = t & 63;
  if (lane == 0) { red[0][wid] = sa; red[1][wid] = sp; red[2][wid] = dp; }
  __syncthreads();
  sa = red[0][0] + red[0][1] + red[0][2] + red[0][3];
  sp = red[1][0] + red[1][1] + red[1][2] + red[1][3];
  dp = red[2][0] + red[2][1] + red[2][2] + red[2][3];
  const float rsa = rsqrtf(sa), rsp = rsqrtf(sp);
  if (t == 0) {
    pos[b] = 1.0f - dp * rsa * rsp;
    ssum[b] = 0.0f;
    scnt[b] = 0;
    smin[b] = 0x7F800000u;  // +inf bits
  }
  ushort4 oa, op;
  oa.x = f2bf(av.x * rsa); oa.y = f2bf(av.y * rsa);
  oa.z = f2bf(av.z * rsa); oa.w = f2bf(av.w * rsa);
  op.x = f2bf(pv.x * rsp); op.y = f2bf(pv.y * rsp);
  op.z = f2bf(pv.z * rsp); op.w = f2bf(pv.w * rsp);
  reinterpret_cast<ushort4*>(reinterpret_cast<unsigned short*>(Ah) + (size_t)b * ND)[t] = oa;
  reinterpret_cast<ushort4*>(reinterpret_cast<unsigned short*>(Ph) + (size_t)b * ND)[t] = op;
}

// ---- Kernel 2: 256x256 8-phase GEMM fused with per-row semi-hard stats ---
// BM=BN=256, BK=64, 8 waves (2Mx4N), 512 thr, 128 KiB LDS double-buffer.
// LDS planes (byte offsets in dynamic smem):
//   A buf0: 0       A buf1: 32768   B buf0: 65536   B buf1: 98304
// Plane layout: [256 rows][64 bf16] = 128 B/row; XOR-swizzle byte^=((row&7)<<4)
// realized as linear LDS dest + inverse-swizzled GLOBAL source (rule 21).

#define BAR   __builtin_amdgcn_s_barrier()
#define LGKM0 asm volatile("s_waitcnt lgkmcnt(0)" ::: "memory")
#define VM4   asm volatile("s_waitcnt vmcnt(4)" ::: "memory")
#define VM0   asm volatile("s_waitcnt vmcnt(0)" ::: "memory")
#define PRIO1 __builtin_amdgcn_s_setprio(1)
#define PRIO0 __builtin_amdgcn_s_setprio(0)

#define STAGE_A(buf, half, kt) do { \
    const char* _g = (const char*)Ah + (size_t)(row0 + (half)*128 + srow) * 2048 + (size_t)(kt)*128 + scolb; \
    char* _l = smem + (buf)*32768 + (half)*16384 + w*1024; \
    gload_lds16(_g, _l); \
    gload_lds16(_g + 64*2048, _l + 8192); \
  } while (0)

#define STAGE_B(buf, half, kt) do { \
    const char* _g = (const char*)Ph + (size_t)(col0 + (half)*128 + srow) * 2048 + (size_t)(kt)*128 + scolb; \
    char* _l = smem + 65536 + (buf)*32768 + (half)*16384 + w*1024; \
    gload_lds16(_g, _l); \
    gload_lds16(_g + 64*2048, _l + 8192); \
  } while (0)

#define LD_A(buf, mh) do { _Pragma("unroll") \
    for (int mm = 0; mm < 4; ++mm) { \
      const char* _p = smem + (buf)*32768 + (wr*128 + (mh)*64 + mm*16 + c) * 128; \
      aq[mm][0] = *(const bf16x8_t*)(_p + cswz0); \
      aq[mm][1] = *(const bf16x8_t*)(_p + cswz1); \
    } } while (0)

#define LD_B(buf, nh, dst) do { _Pragma("unroll") \
    for (int nn = 0; nn < 2; ++nn) { \
      const char* _p = smem + 65536 + (buf)*32768 + (wc*64 + (nh)*32 + nn*16 + c) * 128; \
      dst[nn][0] = *(const bf16x8_t*)(_p + cswz0); \
      dst[nn][1] = *(const bf16x8_t*)(_p + cswz1); \
    } } while (0)

#define MFMA_Q(mh, bq, nh) do { _Pragma("unroll") \
    for (int kk = 0; kk < 2; ++kk) { _Pragma("unroll") \
      for (int mm = 0; mm < 4; ++mm) { _Pragma("unroll") \
        for (int nn = 0; nn < 2; ++nn) \
          acc[(mh)*4+mm][(nh)*2+nn] = __builtin_amdgcn_mfma_f32_16x16x32_bf16( \
              aq[mm][kk], bq[nn][kk], acc[(mh)*4+mm][(nh)*2+nn], 0, 0, 0); \
      } } } while (0)

__global__ __launch_bounds__(512, 2) void gemm8_kernel(
    const __bf16* __restrict__ Ah, const __bf16* __restrict__ Ph,
    const float* __restrict__ pos, float* __restrict__ ssum,
    int* __restrict__ scnt, unsigned* __restrict__ smin) {
  extern __shared__ char smem[];
  const int t = threadIdx.x;
  const int lane = t & 63;
  const int w = t >> 6;
  const int wr = w >> 2, wc = w & 3;     // 2x4 wave grid; wave tile 128x64
  const int c = lane & 15, g = lane >> 4;

  // XCD-aware bijective swizzle (256 blocks, 8 XCDs, 256%8==0)
  const int wg = blockIdx.x;
  const int swzid = (wg & 7) * 32 + (wg >> 3);
  const int by = swzid >> 4, bx = swzid & 15;
  const int row0 = by * 256, col0 = bx * 256;

  // staging map: thread covers rows {w*8+lane/8, +64} of a 128-row half-tile;
  // source column pre-swizzled so linear LDS dest + swizzled read are consistent
  const int srow = w * 8 + (lane >> 3);
  const int scolb = ((lane & 7) << 4) ^ (((lane >> 3) & 7) << 4);
  // read-side swizzled column offsets for kk=0,1 (row&7 == c&7 for all frag rows)
  const int cswz0 = (g * 16) ^ ((c & 7) << 4);
  const int cswz1 = (64 + g * 16) ^ ((c & 7) << 4);

  f32x4_t acc[8][4] = {};
  bf16x8_t aq[4][2], bq0[2][2], bq1[2][2];

  // Prologue: tile0 -> buf0 (B halves then A halves), tile1 B -> buf1.
  // vmcnt(4) leaves only the 2 buf1.B half-tiles in flight; buf0 landed.
  STAGE_B(0, 0, 0); STAGE_B(0, 1, 0);
  STAGE_A(0, 0, 0); STAGE_A(0, 1, 0);
  STAGE_B(1, 0, 1); STAGE_B(1, 1, 1);
  VM4; BAR;

  for (int i = 0; i < NIT; ++i) {
    const int o = 2 * i + 1;
    const bool st = (i < NIT - 1);
    // phase 1: read buf0 A(mh0)+B(nh0); stage buf1.A half0 (tile 2i+1)
    LD_A(0, 0); LD_B(0, 0, bq0);
    STAGE_A(1, 0, o);
    BAR; LGKM0; PRIO1; MFMA_Q(0, bq0, 0); PRIO0; BAR;
    // phase 2: read buf0 B(nh1); stage buf1.A half1
    LD_B(0, 1, bq1);
    STAGE_A(1, 1, o);
    BAR; LGKM0; PRIO1; MFMA_Q(0, bq1, 1); PRIO0; BAR;
    // phase 3: read buf0 A(mh1); stage buf0.B half0 (tile 2i+2; buf0.B reads done @ph2)
    LD_A(0, 1);
    if (st) STAGE_B(0, 0, o + 1);
    BAR; LGKM0; PRIO1; MFMA_Q(1, bq0, 0); PRIO0; BAR;
    // phase 4: stage buf0.B half1; vmcnt ensures buf1 (tile 2i+1) fully landed
    if (st) STAGE_B(0, 1, o + 1);
    PRIO1; MFMA_Q(1, bq1, 1); PRIO0;
    if (st) { VM4; } else { VM0; }
    BAR;
    // phase 5: read buf1 A(mh0)+B(nh0); stage buf0.A half0 (buf0.A reads done @ph3)
    LD_A(1, 0); LD_B(1, 0, bq0);
    if (st) STAGE_A(0, 0, o + 1);
    BAR; LGKM0; PRIO1; MFMA_Q(0, bq0, 0); PRIO0; BAR;
    // phase 6: read buf1 B(nh1); stage buf0.A half1
    LD_B(1, 1, bq1);
    if (st) STAGE_A(0, 1, o + 1);
    BAR; LGKM0; PRIO1; MFMA_Q(0, bq1, 1); PRIO0; BAR;
    // phase 7: read buf1 A(mh1); stage buf1.B half0 (tile 2i+3; buf1.B reads done @ph6)
    LD_A(1, 1);
    if (st) STAGE_B(1, 0, o + 2);
    BAR; LGKM0; PRIO1; MFMA_Q(1, bq0, 0); PRIO0; BAR;
    // phase 8: stage buf1.B half1; vmcnt ensures buf0 (tile 2i+2) fully landed
    if (st) STAGE_B(1, 1, o + 2);
    PRIO1; MFMA_Q(1, bq1, 1); PRIO0;
    if (st) { VM4; } else { VM0; }
    BAR;
  }

  // Epilogue: per-row {sum,cnt,min} over this block's 256-col slice.
  // C frag layout: col = c, row = g*4 + r within each 16x16 tile.
#pragma unroll
  for (int m = 0; m < 8; ++m) {
#pragma unroll
    for (int r = 0; r < 4; ++r) {
      const int grow = row0 + wr * 128 + m * 16 + g * 4 + r;
      const float pd = pos[grow];
      float s = 0.0f;
      int ct = 0;
      float mn = 3.0e38f;
#pragma unroll
      for (int n = 0; n < 4; ++n) {
        const int gcol = col0 + wc * 64 + n * 16 + c;
        const float v = 1.0f - acc[m][n][r];
        if (gcol != grow) {
          mn = fminf(mn, v);
          if (v > pd && v < pd + MARGIN) { s += v; ct += 1; }
        }
      }
#pragma unroll
      for (int off = 1; off < 16; off <<= 1) {
        s += __shfl_xor(s, off);
        ct += __shfl_xor(ct, off);
        mn = fminf(mn, __shfl_xor(mn, off));
      }
      if (c == 0) {
        atomicAdd(&ssum[grow], s);
        atomicAdd(&scnt[grow], ct);
        atomicMin(&smin[grow], __float_as_uint(mn));
      }
    }
  }
}

// ---- Kernel 3: combine per-row stats -> loss -----------------------------
__global__ __launch_bounds__(256) void finalize_kernel(
    const float* __restrict__ pos, const float* __restrict__ ssum,
    const int* __restrict__ scnt, const unsigned* __restrict__ smin,
    float* __restrict__ out) {
  const int t = threadIdx.x;
  float accv = 0.0f;
#pragma unroll
  for (int it = 0; it < NB / 256; ++it) {
    const int rr = t + it * 256;
    const float pd = pos[rr];
    const int ct = scnt[rr];
    const float neg = ct > 0 ? ssum[rr] / (float)ct : __uint_as_float(smin[rr]);
    accv += fmaxf(pd - neg + MARGIN, 0.0f);
  }
#pragma unroll
  for (int off = 1; off < 64; off <<= 1) accv += __shfl_xor(accv, off);
  __shared__ float red[4];
  if ((t & 63) == 0) red[t >> 6] = accv;
  __syncthreads();
  if (t == 0) out[0] = (red[0] + red[1] + red[2] + red[3]) * (1.0f / NB);
}

extern "C" void kernel_launch(void* const* d_in, const int* in_sizes, int n_in,
                              void* d_out, int out_size, void* d_ws, size_t ws_size,
                              hipStream_t stream) {
  const float* za = (const float*)d_in[0];
  const float* zp = (const float*)d_in[1];
  float* out = (float*)d_out;
  char* ws = (char*)d_ws;
  __bf16* Ah = (__bf16*)(ws);                                   // 8 MB
  __bf16* Ph = (__bf16*)(ws + (size_t)NB * ND * 2);             // 8 MB
  float* pos = (float*)(ws + (size_t)NB * ND * 4);              // 16 KB
  float* ssum = pos + NB;                                       // 16 KB
  int* scnt = (int*)(ssum + NB);                                // 16 KB
  unsigned* smin = (unsigned*)(scnt + NB);                      // 16 KB

  (void)hipFuncSetAttribute((const void*)gemm8_kernel,
                            hipFuncAttributeMaxDynamicSharedMemorySize, 131072);

  norm_kernel<<<NB, 256, 0, stream>>>(za, zp, Ah, Ph, pos, ssum, scnt, smin);
  gemm8_kernel<<<256, 512, 131072, stream>>>(Ah, Ph, pos, ssum, scnt, smin);
  finalize_kernel<<<1, 256, 0, stream>>>(pos, ssum, scnt, smin, out);
}